// Round 3
// baseline (2158.160 us; speedup 1.0000x reference)
//
#include <hip/hip_runtime.h>
#include <math.h>

#define S_LEN 1024
#define D_MODEL 512
#define N_HEAD 8
#define DKK 64
#define P_LEN 2047
#define B_SZ 8

union f4u { float4 v; float f[4]; };

// ---------------- mask normalize (handles bool/int32/float storage) -------
__global__ __launch_bounds__(256) void mask_prep(const void* __restrict__ mask,
                                                 int* __restrict__ mw) {
  const unsigned int* u = (const unsigned int*)mask;
  bool all01 = true, allf = true;
#pragma unroll
  for (int j = 0; j < 16; ++j) {
    unsigned int x = u[j];
    all01 &= (x <= 1u);
    allf &= (x == 0u || x == 0x3f800000u);
  }
  int i = blockIdx.x * 256 + threadIdx.x;
  int v;
  if (all01) v = (((const int*)mask)[i] != 0);
  else if (allf) v = (((const float*)mask)[i] != 0.0f);
  else v = (((const unsigned char*)mask)[i] != 0);
  mw[i] = v;
}

// ---------------- generic C = A(MxK) @ W(NxK)^T + bias, K=N=512 -----------
// MODE 0: k/v proj  -> out1 in (B,H,S,DK)
// MODE 1: q proj    -> out1 = +bq+pbu, out2 = +bq+pbv, (B,H,S,DK)
// MODE 2: pos proj  -> out1 in (H,P,DK), no bias, M=2047 (guarded)
// MODE 3: out proj  -> out1 = (M,512) row-major (d_out)
template<int MODE>
__global__ __launch_bounds__(256) void gemm512(
    const float* __restrict__ A, const float* __restrict__ W,
    const float* __restrict__ bias, const float* __restrict__ pbu,
    const float* __restrict__ pbv, float* __restrict__ out1,
    float* __restrict__ out2, int M)
{
  __shared__ float As[64][36];   // [m][k] stride 36 (16B-aligned rows, 2-way max)
  __shared__ float Wt[32][68];   // [k][n] transposed, stride 68
  const int tid = threadIdx.x;
  const int ty = tid >> 4, tx = tid & 15;
  const int m0 = blockIdx.x * 64, n0 = blockIdx.y * 64;
  const int lr = tid >> 3;            // 0..31
  const int lc = (tid & 7) << 2;      // 0,4,...,28
  float acc[4][4] = {};

  for (int k0 = 0; k0 < 512; k0 += 32) {
#pragma unroll
    for (int hh = 0; hh < 2; ++hh) {
      int r = lr + hh * 32;
      int gm = m0 + r;
      float4 av = make_float4(0.f, 0.f, 0.f, 0.f);
      if (gm < M) av = *(const float4*)(A + (size_t)gm * 512 + k0 + lc);
      *(float4*)&As[r][lc] = av;
      float4 wv = *(const float4*)(W + (size_t)(n0 + r) * 512 + k0 + lc);
      Wt[lc + 0][r] = wv.x;
      Wt[lc + 1][r] = wv.y;
      Wt[lc + 2][r] = wv.z;
      Wt[lc + 3][r] = wv.w;
    }
    __syncthreads();
#pragma unroll
    for (int kk = 0; kk < 32; kk += 4) {
      f4u a[4], w[4];
#pragma unroll
      for (int i = 0; i < 4; ++i) a[i].v = *(float4*)&As[ty * 4 + i][kk];
#pragma unroll
      for (int q = 0; q < 4; ++q) w[q].v = *(float4*)&Wt[kk + q][tx * 4];
#pragma unroll
      for (int i = 0; i < 4; ++i)
#pragma unroll
        for (int q = 0; q < 4; ++q)
#pragma unroll
          for (int j = 0; j < 4; ++j)
            acc[i][j] = fmaf(a[i].f[q], w[q].f[j], acc[i][j]);
    }
    __syncthreads();
  }

  // ---- epilogue: vectorized float4 stores (cols n0+tx*4 .. +3 contiguous;
  // for MODE 0/1/2 they stay inside one head since DK=64 is a multiple of 4)
#pragma unroll
  for (int i = 0; i < 4; ++i) {
    int m = m0 + ty * 4 + i;
    if (MODE == 2 && m >= M) continue;
    int n = n0 + tx * 4;
    f4u r;
#pragma unroll
    for (int j = 0; j < 4; ++j) r.f[j] = acc[i][j];
    if constexpr (MODE == 0) {
#pragma unroll
      for (int j = 0; j < 4; ++j) r.f[j] += bias[n + j];
      int b = m >> 10, s = m & 1023, h = n >> 6, dk = n & 63;
      *(float4*)(out1 + (size_t)(((b * 8 + h) << 10) + s) * 64 + dk) = r.v;
    } else if constexpr (MODE == 1) {
      f4u ru, rv;
#pragma unroll
      for (int j = 0; j < 4; ++j) {
        float t = r.f[j] + bias[n + j];
        ru.f[j] = t + pbu[n + j];
        rv.f[j] = t + pbv[n + j];
      }
      int b = m >> 10, s = m & 1023, h = n >> 6, dk = n & 63;
      size_t idx = (size_t)(((b * 8 + h) << 10) + s) * 64 + dk;
      *(float4*)(out1 + idx) = ru.v;
      *(float4*)(out2 + idx) = rv.v;
    } else if constexpr (MODE == 2) {
      int h = n >> 6, dk = n & 63;
      *(float4*)(out1 + (size_t)(h * P_LEN + m) * 64 + dk) = r.v;
    } else {
#pragma unroll
      for (int j = 0; j < 4; ++j) r.f[j] += bias[n + j];
      *(float4*)(out1 + (size_t)m * 512 + n) = r.v;
    }
  }
}

// ---------------- fused rel-pos flash attention ---------------------------
// grid (S/32, B*H), 256 thr. Per block: q rows [s0,s0+32), stream keys in
// 32-tiles. bd computed DIAGONALLY: thread (ty,tx) covers rows r=2ty+i,
// cols t=2tx+j; bd[i][j] = qv[r] . band[ubase+j-i], ubase = 2tx-2ty+31.
__global__ __launch_bounds__(256) void attn_kernel(
    const float* __restrict__ qu, const float* __restrict__ qv,
    const float* __restrict__ kh, const float* __restrict__ vh,
    const float* __restrict__ pp, const int* __restrict__ mw,
    float* __restrict__ ctx)
{
  __shared__ float qu_s[32][68], qv_s[32][68];
  __shared__ float kh_s[32][68], vh_s[32][68];
  __shared__ float band_s[63][68];
  __shared__ float P_s[32][36];

  const int tid = threadIdx.x;
  const int ty = tid >> 4, tx = tid & 15;
  const int s0 = blockIdx.x * 32;
  const int bh = blockIdx.y;
  const int b = bh >> 3, h = bh & 7;
  const int ubase = 2 * tx - 2 * ty + 31;   // in [1,61]

  const float* quB = qu + (size_t)bh * S_LEN * 64;
  const float* qvB = qv + (size_t)bh * S_LEN * 64;
  const float* khB = kh + (size_t)bh * S_LEN * 64;
  const float* vhB = vh + (size_t)bh * S_LEN * 64;
  const float* ppH = pp + (size_t)h * P_LEN * 64;

  for (int idx = tid; idx < 32 * 16; idx += 256) {
    int r = idx >> 4, c = (idx & 15) << 2;
    *(float4*)&qu_s[r][c] = *(const float4*)(quB + (size_t)(s0 + r) * 64 + c);
    *(float4*)&qv_s[r][c] = *(const float4*)(qvB + (size_t)(s0 + r) * 64 + c);
  }

  float m_run[2] = {-1e30f, -1e30f};
  float l_run[2] = {0.f, 0.f};
  float o[2][4] = {};

  for (int t0 = 0; t0 < S_LEN; t0 += 32) {
    // ---- stage K/V tile + pos band (p = pmin + u, u in [0,63))
    for (int idx = tid; idx < 32 * 16; idx += 256) {
      int r = idx >> 4, c = (idx & 15) << 2;
      *(float4*)&kh_s[r][c] = *(const float4*)(khB + (size_t)(t0 + r) * 64 + c);
      *(float4*)&vh_s[r][c] = *(const float4*)(vhB + (size_t)(t0 + r) * 64 + c);
    }
    const int pmin = S_LEN + t0 - s0 - 31;   // >= 1 always
    for (int idx = tid; idx < 63 * 16; idx += 256) {
      int r = idx >> 4, c = (idx & 15) << 2;
      int p = pmin + r;
      float4 bv = make_float4(0.f, 0.f, 0.f, 0.f);
      if (p < P_LEN) bv = *(const float4*)(ppH + (size_t)p * 64 + c);
      *(float4*)&band_s[r][c] = bv;
    }
    __syncthreads();

    // ---- fused ac + diagonal bd (2x2 micro, 9 ds_read_b128 / 32 FMA per d)
    float ac[2][2] = {};
    float bd[2][2] = {};
#pragma unroll
    for (int d = 0; d < 64; d += 4) {
      f4u qa0, qa1, qb0, qb1, k0v, k1v, bm, b0, bp;
      qa0.v = *(float4*)&qu_s[2 * ty + 0][d];
      qa1.v = *(float4*)&qu_s[2 * ty + 1][d];
      qb0.v = *(float4*)&qv_s[2 * ty + 0][d];
      qb1.v = *(float4*)&qv_s[2 * ty + 1][d];
      k0v.v = *(float4*)&kh_s[2 * tx + 0][d];
      k1v.v = *(float4*)&kh_s[2 * tx + 1][d];
      bm.v  = *(float4*)&band_s[ubase - 1][d];   // u for (i=1,j=0)
      b0.v  = *(float4*)&band_s[ubase + 0][d];   // u for (i==j)
      bp.v  = *(float4*)&band_s[ubase + 1][d];   // u for (i=0,j=1)
#pragma unroll
      for (int q = 0; q < 4; ++q) {
        ac[0][0] = fmaf(qa0.f[q], k0v.f[q], ac[0][0]);
        ac[0][1] = fmaf(qa0.f[q], k1v.f[q], ac[0][1]);
        ac[1][0] = fmaf(qa1.f[q], k0v.f[q], ac[1][0]);
        ac[1][1] = fmaf(qa1.f[q], k1v.f[q], ac[1][1]);
        bd[0][0] = fmaf(qb0.f[q], b0.f[q], bd[0][0]);
        bd[0][1] = fmaf(qb0.f[q], bp.f[q], bd[0][1]);
        bd[1][0] = fmaf(qb1.f[q], bm.f[q], bd[1][0]);
        bd[1][1] = fmaf(qb1.f[q], b0.f[q], bd[1][1]);
      }
    }

    // ---- combine + mask + online softmax
#pragma unroll
    for (int i = 0; i < 2; ++i) {
      int r = 2 * ty + i;
      float sc[2];
#pragma unroll
      for (int j = 0; j < 2; ++j) {
        int tj = 2 * tx + j;
        float bdv = bd[i][j];
        // rel_shift wrap element: z[0,S-1] = qv[1] . pp[0]
        if (s0 == 0 && r == 0 && t0 == S_LEN - 32 && tj == 31) {
          float w = 0.f;
          for (int d = 0; d < 64; ++d) w = fmaf(qv_s[1][d], ppH[d], w);
          bdv = w;
        }
        float v = (ac[i][j] + bdv) * 0.125f;
        if (mw[b * S_LEN + t0 + tj]) v = -10000.0f;
        sc[j] = v;
      }
      float tm = fmaxf(sc[0], sc[1]);
#pragma unroll
      for (int off = 1; off < 16; off <<= 1) tm = fmaxf(tm, __shfl_xor(tm, off));
      float mn = fmaxf(m_run[i], tm);
      float corr = __expf(m_run[i] - mn);
      float p0 = __expf(sc[0] - mn);
      float p1 = __expf(sc[1] - mn);
      float ps = p0 + p1;
#pragma unroll
      for (int off = 1; off < 16; off <<= 1) ps += __shfl_xor(ps, off);
      l_run[i] = l_run[i] * corr + ps;
      m_run[i] = mn;
#pragma unroll
      for (int j = 0; j < 4; ++j) o[i][j] *= corr;
      P_s[r][2 * tx + 0] = p0;
      P_s[r][2 * tx + 1] = p1;
    }
    __syncthreads();

    // ---- PV: o += P . V (cols 4tx+j)
#pragma unroll
    for (int t = 0; t < 32; t += 4) {
      f4u p0, p1;
      p0.v = *(float4*)&P_s[2 * ty + 0][t];
      p1.v = *(float4*)&P_s[2 * ty + 1][t];
#pragma unroll
      for (int q = 0; q < 4; ++q) {
        f4u vv;
        vv.v = *(float4*)&vh_s[t + q][4 * tx];
#pragma unroll
        for (int j = 0; j < 4; ++j) {
          o[0][j] = fmaf(p0.f[q], vv.f[j], o[0][j]);
          o[1][j] = fmaf(p1.f[q], vv.f[j], o[1][j]);
        }
      }
    }
    __syncthreads();
  }

#pragma unroll
  for (int i = 0; i < 2; ++i) {
    int s = s0 + 2 * ty + i;
    float inv = 1.0f / l_run[i];
    f4u r;
#pragma unroll
    for (int j = 0; j < 4; ++j) r.f[j] = o[i][j] * inv;
    *(float4*)(ctx + ((size_t)b * S_LEN + s) * 512 + h * 64 + 4 * tx) = r.v;
  }
}

// --------------------------------------------------------------------------
extern "C" void kernel_launch(void* const* d_in, const int* in_sizes, int n_in,
                              void* d_out, int out_size, void* d_ws, size_t ws_size,
                              hipStream_t stream) {
  const float* q    = (const float*)d_in[0];
  const float* k    = (const float*)d_in[1];
  const float* v    = (const float*)d_in[2];
  const float* pos  = (const float*)d_in[3];
  const void*  mask = d_in[4];
  const float* Wq   = (const float*)d_in[5];
  const float* bq   = (const float*)d_in[6];
  const float* Wk   = (const float*)d_in[7];
  const float* bk   = (const float*)d_in[8];
  const float* Wv   = (const float*)d_in[9];
  const float* bv   = (const float*)d_in[10];
  const float* Wo   = (const float*)d_in[11];
  const float* bo   = (const float*)d_in[12];
  const float* Wpos = (const float*)d_in[13];
  const float* pbu  = (const float*)d_in[14];
  const float* pbv  = (const float*)d_in[15];
  float* out = (float*)d_out;

  float* ws = (float*)d_ws;
  const size_t SZ_BHSD = (size_t)B_SZ * N_HEAD * S_LEN * DKK;  // 4.19M
  const size_t SZ_PP   = (size_t)N_HEAD * P_LEN * DKK;         // 1.05M
  float* quW  = ws;
  float* qvW  = quW + SZ_BHSD;
  float* khW  = qvW + SZ_BHSD;
  float* vhW  = khW + SZ_BHSD;
  float* ppW  = vhW + SZ_BHSD;
  float* ctxW = ppW + SZ_PP;
  int*   mwW  = (int*)(ctxW + SZ_BHSD);

  mask_prep<<<dim3(B_SZ * S_LEN / 256), 256, 0, stream>>>(mask, mwW);

  gemm512<1><<<dim3(128, 8), 256, 0, stream>>>(q, Wq, bq, pbu, pbv, quW, qvW, 8192);
  gemm512<0><<<dim3(128, 8), 256, 0, stream>>>(k, Wk, bk, nullptr, nullptr, khW, nullptr, 8192);
  gemm512<0><<<dim3(128, 8), 256, 0, stream>>>(v, Wv, bv, nullptr, nullptr, vhW, nullptr, 8192);
  gemm512<2><<<dim3(32, 8), 256, 0, stream>>>(pos, Wpos, nullptr, nullptr, nullptr, ppW, nullptr, P_LEN);

  attn_kernel<<<dim3(S_LEN / 32, B_SZ * N_HEAD), 256, 0, stream>>>(
      quW, qvW, khW, vhW, ppW, mwW, ctxW);

  gemm512<3><<<dim3(128, 8), 256, 0, stream>>>(ctxW, Wo, bo, nullptr, nullptr, out, nullptr, 8192);
}

// Round 5
// 1478.305 us; speedup vs baseline: 1.4599x; 1.4599x over previous
//
#include <hip/hip_runtime.h>
#include <math.h>

#define S_LEN 1024
#define D_MODEL 512
#define N_HEAD 8
#define DKK 64
#define P_LEN 2047
#define B_SZ 8

#define QT 32
#define KT 64
#define BAND_ROWS 95   // u = t - r + 31, t in [0,64), r in [0,32)

union f4u { float4 v; float f[4]; };

// swizzled LDS index: row stride 64 floats, 16B-granule XOR by (r>>2)&7.
// Bank-group of float f is (f>>2)&7; this spreads row-per-lane b128 access
// patterns (rows stepping by 4 across tx) over all 8 groups -> <=2-way.
__device__ __forceinline__ int SW(int r, int c) {
  return (r << 6) + (c ^ (((r >> 2) & 7) << 2));
}

// ---------------- mask normalize (handles bool/int32/float storage) -------
__global__ __launch_bounds__(256) void mask_prep(const void* __restrict__ mask,
                                                 int* __restrict__ mw) {
  const unsigned int* u = (const unsigned int*)mask;
  bool all01 = true, allf = true;
#pragma unroll
  for (int j = 0; j < 16; ++j) {
    unsigned int x = u[j];
    all01 &= (x <= 1u);
    allf &= (x == 0u || x == 0x3f800000u);
  }
  int i = blockIdx.x * 256 + threadIdx.x;
  int v;
  if (all01) v = (((const int*)mask)[i] != 0);
  else if (allf) v = (((const float*)mask)[i] != 0.0f);
  else v = (((const unsigned char*)mask)[i] != 0);
  mw[i] = v;
}

// ---------------- generic C = A(MxK) @ W(NxK)^T + bias, K=N=512 -----------
template<int MODE>
__global__ __launch_bounds__(256) void gemm512(
    const float* __restrict__ A, const float* __restrict__ W,
    const float* __restrict__ bias, const float* __restrict__ pbu,
    const float* __restrict__ pbv, float* __restrict__ out1,
    float* __restrict__ out2, int M)
{
  __shared__ float As[64][36];
  __shared__ float Wt[32][68];
  const int tid = threadIdx.x;
  const int ty = tid >> 4, tx = tid & 15;
  const int m0 = blockIdx.x * 64, n0 = blockIdx.y * 64;
  const int lr = tid >> 3;
  const int lc = (tid & 7) << 2;
  float acc[4][4] = {};

  for (int k0 = 0; k0 < 512; k0 += 32) {
#pragma unroll
    for (int hh = 0; hh < 2; ++hh) {
      int r = lr + hh * 32;
      int gm = m0 + r;
      float4 av = make_float4(0.f, 0.f, 0.f, 0.f);
      if (gm < M) av = *(const float4*)(A + (size_t)gm * 512 + k0 + lc);
      *(float4*)&As[r][lc] = av;
      float4 wv = *(const float4*)(W + (size_t)(n0 + r) * 512 + k0 + lc);
      Wt[lc + 0][r] = wv.x;
      Wt[lc + 1][r] = wv.y;
      Wt[lc + 2][r] = wv.z;
      Wt[lc + 3][r] = wv.w;
    }
    __syncthreads();
#pragma unroll
    for (int kk = 0; kk < 32; kk += 4) {
      f4u a[4], w[4];
#pragma unroll
      for (int i = 0; i < 4; ++i) a[i].v = *(float4*)&As[ty * 4 + i][kk];
#pragma unroll
      for (int q = 0; q < 4; ++q) w[q].v = *(float4*)&Wt[kk + q][tx * 4];
#pragma unroll
      for (int i = 0; i < 4; ++i)
#pragma unroll
        for (int q = 0; q < 4; ++q)
#pragma unroll
          for (int j = 0; j < 4; ++j)
            acc[i][j] = fmaf(a[i].f[q], w[q].f[j], acc[i][j]);
    }
    __syncthreads();
  }

#pragma unroll
  for (int i = 0; i < 4; ++i) {
    int m = m0 + ty * 4 + i;
    if (MODE == 2 && m >= M) continue;
    int n = n0 + tx * 4;
    f4u r;
#pragma unroll
    for (int j = 0; j < 4; ++j) r.f[j] = acc[i][j];
    if constexpr (MODE == 0) {
#pragma unroll
      for (int j = 0; j < 4; ++j) r.f[j] += bias[n + j];
      int b = m >> 10, s = m & 1023, h = n >> 6, dk = n & 63;
      *(float4*)(out1 + (size_t)(((b * 8 + h) << 10) + s) * 64 + dk) = r.v;
    } else if constexpr (MODE == 1) {
      f4u ru, rv;
#pragma unroll
      for (int j = 0; j < 4; ++j) {
        float t = r.f[j] + bias[n + j];
        ru.f[j] = t + pbu[n + j];
        rv.f[j] = t + pbv[n + j];
      }
      int b = m >> 10, s = m & 1023, h = n >> 6, dk = n & 63;
      size_t idx = (size_t)(((b * 8 + h) << 10) + s) * 64 + dk;
      *(float4*)(out1 + idx) = ru.v;
      *(float4*)(out2 + idx) = rv.v;
    } else if constexpr (MODE == 2) {
      int h = n >> 6, dk = n & 63;
      *(float4*)(out1 + (size_t)(h * P_LEN + m) * 64 + dk) = r.v;
    } else {
#pragma unroll
      for (int j = 0; j < 4; ++j) r.f[j] += bias[n + j];
      *(float4*)(out1 + (size_t)m * 512 + n) = r.v;
    }
  }
}

// ---------------- fused rel-pos flash attention ---------------------------
// grid (S/QT, B*H), 256 thr. Q-tile 32 rows, K-tile 64 keys.
// Thread (ty,tx): ty=tid>>4 rows {2ty,2ty+1}; tx=tid&15.
//   score phase: cols t = 4tx..4tx+3 (keys)
//   PV phase:    cols dk = 4tx..4tx+3 (head dim), P via LDS (intra-16-lane)
__global__ __launch_bounds__(256, 2) void attn_kernel(
    const float* __restrict__ qu, const float* __restrict__ qv,
    const float* __restrict__ kh, const float* __restrict__ vh,
    const float* __restrict__ pp, const int* __restrict__ mw,
    float* __restrict__ ctx)
{
  __shared__ float qu_s[QT * 64], qv_s[QT * 64];
  __shared__ float kh_s[KT * 64], vh_s[KT * 64];
  __shared__ float band_s[BAND_ROWS * 64];
  __shared__ float P_s[QT * 64];

  const int tid = threadIdx.x;
  const int ty = tid >> 4, tx = tid & 15;
  const int s0 = blockIdx.x * QT;
  const int bh = blockIdx.y;
  const int b = bh >> 3, h = bh & 7;

  const float* quB = qu + (size_t)bh * S_LEN * 64;
  const float* qvB = qv + (size_t)bh * S_LEN * 64;
  const float* khB = kh + (size_t)bh * S_LEN * 64;
  const float* vhB = vh + (size_t)bh * S_LEN * 64;
  const float* ppH = pp + (size_t)h * P_LEN * 64;

  // stage q tiles (swizzled)
#pragma unroll
  for (int it = 0; it < 2; ++it) {
    int idx = tid + it * 256;
    int r = idx >> 4, c = (idx & 15) << 2;
    *(float4*)&qu_s[SW(r, c)] = *(const float4*)(quB + (size_t)(s0 + r) * 64 + c);
    *(float4*)&qv_s[SW(r, c)] = *(const float4*)(qvB + (size_t)(s0 + r) * 64 + c);
  }
  __syncthreads();

  // rel_shift wrap element: z[0,S-1] = qv[1] . pp[0]  (only s0==0 blocks)
  float wrapW = 0.f;
  if (s0 == 0) {
    for (int d = 0; d < 64; ++d)
      wrapW = fmaf(qv_s[64 + d], ppH[d], wrapW);   // SW(1,d)=64+d
  }
  const bool wrapT = (s0 == 0) && (ty == 0) && (tx == 15);

  float m_run[2] = {-1e30f, -1e30f};
  float l_run[2] = {0.f, 0.f};
  float o[2][4] = {};
  const int ub = 4 * tx - 2 * ty + 31;   // band row for (i=0,j=0); offsets -1..+3

  for (int t0 = 0; t0 < S_LEN; t0 += KT) {
    // ---- stage K/V (64 rows) + band (95 rows), all swizzled
#pragma unroll
    for (int it = 0; it < 4; ++it) {
      int idx = tid + it * 256;
      int r = idx >> 4, c = (idx & 15) << 2;
      *(float4*)&kh_s[SW(r, c)] = *(const float4*)(khB + (size_t)(t0 + r) * 64 + c);
      *(float4*)&vh_s[SW(r, c)] = *(const float4*)(vhB + (size_t)(t0 + r) * 64 + c);
    }
    const int pmin = 993 + t0 - s0;   // band_s[u] = pp[pmin+u], u in [0,95)
#pragma unroll
    for (int it = 0; it < 6; ++it) {
      int idx = tid + it * 256;
      if (idx < BAND_ROWS * 16) {
        int r = idx >> 4, c = (idx & 15) << 2;
        int p = pmin + r;
        float4 bv = make_float4(0.f, 0.f, 0.f, 0.f);
        if (p < P_LEN) bv = *(const float4*)(ppH + (size_t)p * 64 + c);
        *(float4*)&band_s[SW(r, c)] = bv;
      }
    }
    __syncthreads();

    // ---- ac[i][j] = qu[2ty+i] . k[4tx+j]
    float ac[2][4] = {};
#pragma unroll
    for (int d = 0; d < 64; d += 4) {
      f4u qa0, qa1, kv0, kv1, kv2, kv3;
      qa0.v = *(float4*)&qu_s[SW(2 * ty + 0, d)];
      qa1.v = *(float4*)&qu_s[SW(2 * ty + 1, d)];
      kv0.v = *(float4*)&kh_s[SW(4 * tx + 0, d)];
      kv1.v = *(float4*)&kh_s[SW(4 * tx + 1, d)];
      kv2.v = *(float4*)&kh_s[SW(4 * tx + 2, d)];
      kv3.v = *(float4*)&kh_s[SW(4 * tx + 3, d)];
#pragma unroll
      for (int e = 0; e < 4; ++e) {
        ac[0][0] = fmaf(qa0.f[e], kv0.f[e], ac[0][0]);
        ac[0][1] = fmaf(qa0.f[e], kv1.f[e], ac[0][1]);
        ac[0][2] = fmaf(qa0.f[e], kv2.f[e], ac[0][2]);
        ac[0][3] = fmaf(qa0.f[e], kv3.f[e], ac[0][3]);
        ac[1][0] = fmaf(qa1.f[e], kv0.f[e], ac[1][0]);
        ac[1][1] = fmaf(qa1.f[e], kv1.f[e], ac[1][1]);
        ac[1][2] = fmaf(qa1.f[e], kv2.f[e], ac[1][2]);
        ac[1][3] = fmaf(qa1.f[e], kv3.f[e], ac[1][3]);
      }
    }

    // ---- bd[i][j] = qv[2ty+i] . band[ub + j - i]
    float bd[2][4] = {};
#pragma unroll
    for (int d = 0; d < 64; d += 4) {
      f4u qb0, qb1, b0, b1, b2, b3, b4;
      qb0.v = *(float4*)&qv_s[SW(2 * ty + 0, d)];
      qb1.v = *(float4*)&qv_s[SW(2 * ty + 1, d)];
      b0.v = *(float4*)&band_s[SW(ub - 1, d)];
      b1.v = *(float4*)&band_s[SW(ub + 0, d)];
      b2.v = *(float4*)&band_s[SW(ub + 1, d)];
      b3.v = *(float4*)&band_s[SW(ub + 2, d)];
      b4.v = *(float4*)&band_s[SW(ub + 3, d)];
#pragma unroll
      for (int e = 0; e < 4; ++e) {
        bd[0][0] = fmaf(qb0.f[e], b1.f[e], bd[0][0]);
        bd[0][1] = fmaf(qb0.f[e], b2.f[e], bd[0][1]);
        bd[0][2] = fmaf(qb0.f[e], b3.f[e], bd[0][2]);
        bd[0][3] = fmaf(qb0.f[e], b4.f[e], bd[0][3]);
        bd[1][0] = fmaf(qb1.f[e], b0.f[e], bd[1][0]);
        bd[1][1] = fmaf(qb1.f[e], b1.f[e], bd[1][1]);
        bd[1][2] = fmaf(qb1.f[e], b2.f[e], bd[1][2]);
        bd[1][3] = fmaf(qb1.f[e], b3.f[e], bd[1][3]);
      }
    }

    // ---- mask + online softmax (row r spans 16 lanes: shfl width 16)
    const int4 m4 = *(const int4*)(mw + (size_t)b * S_LEN + t0 + 4 * tx);
    const int mm[4] = {m4.x, m4.y, m4.z, m4.w};
#pragma unroll
    for (int i = 0; i < 2; ++i) {
      float sc[4];
#pragma unroll
      for (int j = 0; j < 4; ++j) {
        float bdv = bd[i][j];
        if (wrapT && i == 0 && j == 3 && t0 == S_LEN - KT) bdv = wrapW;
        float v = (ac[i][j] + bdv) * 0.125f;
        if (mm[j]) v = -10000.0f;
        sc[j] = v;
      }
      float tm = fmaxf(fmaxf(sc[0], sc[1]), fmaxf(sc[2], sc[3]));
#pragma unroll
      for (int off = 1; off < 16; off <<= 1) tm = fmaxf(tm, __shfl_xor(tm, off));
      float mn = fmaxf(m_run[i], tm);
      float corr = __expf(m_run[i] - mn);
      m_run[i] = mn;
      f4u pw;
      float ps = 0.f;
#pragma unroll
      for (int j = 0; j < 4; ++j) { pw.f[j] = __expf(sc[j] - mn); ps += pw.f[j]; }
#pragma unroll
      for (int off = 1; off < 16; off <<= 1) ps += __shfl_xor(ps, off);
      l_run[i] = l_run[i] * corr + ps;
#pragma unroll
      for (int j = 0; j < 4; ++j) o[i][j] *= corr;
      *(float4*)&P_s[SW(2 * ty + i, 4 * tx)] = pw.v;
    }
    // P_s exchange is within each 16-lane group -> no barrier needed

    // ---- PV: o[i][j] += sum_t P[2ty+i][t] * V[t][4tx+j]
#pragma unroll
    for (int t = 0; t < KT; t += 4) {
      f4u p0, p1, vv0, vv1, vv2, vv3;
      p0.v = *(float4*)&P_s[SW(2 * ty + 0, t)];
      p1.v = *(float4*)&P_s[SW(2 * ty + 1, t)];
      vv0.v = *(float4*)&vh_s[SW(t + 0, 4 * tx)];
      vv1.v = *(float4*)&vh_s[SW(t + 1, 4 * tx)];
      vv2.v = *(float4*)&vh_s[SW(t + 2, 4 * tx)];
      vv3.v = *(float4*)&vh_s[SW(t + 3, 4 * tx)];
#pragma unroll
      for (int j = 0; j < 4; ++j) {
        o[0][j] = fmaf(p0.f[0], vv0.f[j], o[0][j]);
        o[0][j] = fmaf(p0.f[1], vv1.f[j], o[0][j]);
        o[0][j] = fmaf(p0.f[2], vv2.f[j], o[0][j]);
        o[0][j] = fmaf(p0.f[3], vv3.f[j], o[0][j]);
        o[1][j] = fmaf(p1.f[0], vv0.f[j], o[1][j]);
        o[1][j] = fmaf(p1.f[1], vv1.f[j], o[1][j]);
        o[1][j] = fmaf(p1.f[2], vv2.f[j], o[1][j]);
        o[1][j] = fmaf(p1.f[3], vv3.f[j], o[1][j]);
      }
    }
    __syncthreads();   // protect kh/vh/band before next staging
  }

#pragma unroll
  for (int i = 0; i < 2; ++i) {
    int s = s0 + 2 * ty + i;
    float inv = 1.0f / l_run[i];
    f4u r;
#pragma unroll
    for (int j = 0; j < 4; ++j) r.f[j] = o[i][j] * inv;
    *(float4*)(ctx + ((size_t)b * S_LEN + s) * 512 + h * 64 + 4 * tx) = r.v;
  }
}

// --------------------------------------------------------------------------
extern "C" void kernel_launch(void* const* d_in, const int* in_sizes, int n_in,
                              void* d_out, int out_size, void* d_ws, size_t ws_size,
                              hipStream_t stream) {
  const float* q    = (const float*)d_in[0];
  const float* k    = (const float*)d_in[1];
  const float* v    = (const float*)d_in[2];
  const float* pos  = (const float*)d_in[3];
  const void*  mask = d_in[4];
  const float* Wq   = (const float*)d_in[5];
  const float* bq   = (const float*)d_in[6];
  const float* Wk   = (const float*)d_in[7];
  const float* bk   = (const float*)d_in[8];
  const float* Wv   = (const float*)d_in[9];
  const float* bv   = (const float*)d_in[10];
  const float* Wo   = (const float*)d_in[11];
  const float* bo   = (const float*)d_in[12];
  const float* Wpos = (const float*)d_in[13];
  const float* pbu  = (const float*)d_in[14];
  const float* pbv  = (const float*)d_in[15];
  float* out = (float*)d_out;

  float* ws = (float*)d_ws;
  const size_t SZ_BHSD = (size_t)B_SZ * N_HEAD * S_LEN * DKK;
  const size_t SZ_PP   = (size_t)N_HEAD * P_LEN * DKK;
  float* quW  = ws;
  float* qvW  = quW + SZ_BHSD;
  float* khW  = qvW + SZ_BHSD;
  float* vhW  = khW + SZ_BHSD;
  float* ppW  = vhW + SZ_BHSD;
  float* ctxW = ppW + SZ_PP;
  int*   mwW  = (int*)(ctxW + SZ_BHSD);

  mask_prep<<<dim3(B_SZ * S_LEN / 256), 256, 0, stream>>>(mask, mwW);

  gemm512<1><<<dim3(128, 8), 256, 0, stream>>>(q, Wq, bq, pbu, pbv, quW, qvW, 8192);
  gemm512<0><<<dim3(128, 8), 256, 0, stream>>>(k, Wk, bk, nullptr, nullptr, khW, nullptr, 8192);
  gemm512<0><<<dim3(128, 8), 256, 0, stream>>>(v, Wv, bv, nullptr, nullptr, vhW, nullptr, 8192);
  gemm512<2><<<dim3(32, 8), 256, 0, stream>>>(pos, Wpos, nullptr, nullptr, nullptr, ppW, nullptr, P_LEN);

  attn_kernel<<<dim3(S_LEN / QT, B_SZ * N_HEAD), 256, 0, stream>>>(
      quW, qvW, khW, vhW, ppW, mwW, ctxW);

  gemm512<3><<<dim3(128, 8), 256, 0, stream>>>(ctxW, Wo, bo, nullptr, nullptr, out, nullptr, 8192);
}

// Round 6
// 1163.437 us; speedup vs baseline: 1.8550x; 1.2706x over previous
//
#include <hip/hip_runtime.h>
#include <math.h>

#define S_LEN 1024
#define D_MODEL 512
#define N_HEAD 8
#define DKK 64
#define P_LEN 2047
#define B_SZ 8

#define QT 32
#define KT 64
#define BAND_ROWS 95   // u = t - r + 31, t in [0,64), r in [0,32)

union f4u { float4 v; float f[4]; };

// swizzled LDS index: row stride 64 floats, 16B-granule XOR by (r>>2)&7.
__device__ __forceinline__ int SW(int r, int c) {
  return (r << 6) + (c ^ (((r >> 2) & 7) << 2));
}

// ---------------- mask normalize (handles bool/int32/float storage) -------
__global__ __launch_bounds__(256) void mask_prep(const void* __restrict__ mask,
                                                 int* __restrict__ mw) {
  const unsigned int* u = (const unsigned int*)mask;
  bool all01 = true, allf = true;
#pragma unroll
  for (int j = 0; j < 16; ++j) {
    unsigned int x = u[j];
    all01 &= (x <= 1u);
    allf &= (x == 0u || x == 0x3f800000u);
  }
  int i = blockIdx.x * 256 + threadIdx.x;
  int v;
  if (all01) v = (((const int*)mask)[i] != 0);
  else if (allf) v = (((const float*)mask)[i] != 0.0f);
  else v = (((const unsigned char*)mask)[i] != 0);
  mw[i] = v;
}

// ---------------- generic C = A(MxK) @ W(NxK)^T + bias, K=N=512 -----------
template<int MODE>
__global__ __launch_bounds__(256) void gemm512(
    const float* __restrict__ A, const float* __restrict__ W,
    const float* __restrict__ bias, const float* __restrict__ pbu,
    const float* __restrict__ pbv, float* __restrict__ out1,
    float* __restrict__ out2, int M)
{
  __shared__ float As[64][36];
  __shared__ float Wt[32][68];
  const int tid = threadIdx.x;
  const int ty = tid >> 4, tx = tid & 15;
  const int m0 = blockIdx.x * 64, n0 = blockIdx.y * 64;
  const int lr = tid >> 3;
  const int lc = (tid & 7) << 2;
  float acc[4][4] = {};

  for (int k0 = 0; k0 < 512; k0 += 32) {
#pragma unroll
    for (int hh = 0; hh < 2; ++hh) {
      int r = lr + hh * 32;
      int gm = m0 + r;
      float4 av = make_float4(0.f, 0.f, 0.f, 0.f);
      if (gm < M) av = *(const float4*)(A + (size_t)gm * 512 + k0 + lc);
      *(float4*)&As[r][lc] = av;
      float4 wv = *(const float4*)(W + (size_t)(n0 + r) * 512 + k0 + lc);
      Wt[lc + 0][r] = wv.x;
      Wt[lc + 1][r] = wv.y;
      Wt[lc + 2][r] = wv.z;
      Wt[lc + 3][r] = wv.w;
    }
    __syncthreads();
#pragma unroll
    for (int kk = 0; kk < 32; kk += 4) {
      f4u a[4], w[4];
#pragma unroll
      for (int i = 0; i < 4; ++i) a[i].v = *(float4*)&As[ty * 4 + i][kk];
#pragma unroll
      for (int q = 0; q < 4; ++q) w[q].v = *(float4*)&Wt[kk + q][tx * 4];
#pragma unroll
      for (int i = 0; i < 4; ++i)
#pragma unroll
        for (int q = 0; q < 4; ++q)
#pragma unroll
          for (int j = 0; j < 4; ++j)
            acc[i][j] = fmaf(a[i].f[q], w[q].f[j], acc[i][j]);
    }
    __syncthreads();
  }

#pragma unroll
  for (int i = 0; i < 4; ++i) {
    int m = m0 + ty * 4 + i;
    if (MODE == 2 && m >= M) continue;
    int n = n0 + tx * 4;
    f4u r;
#pragma unroll
    for (int j = 0; j < 4; ++j) r.f[j] = acc[i][j];
    if constexpr (MODE == 0) {
#pragma unroll
      for (int j = 0; j < 4; ++j) r.f[j] += bias[n + j];
      int b = m >> 10, s = m & 1023, h = n >> 6, dk = n & 63;
      *(float4*)(out1 + (size_t)(((b * 8 + h) << 10) + s) * 64 + dk) = r.v;
    } else if constexpr (MODE == 1) {
      f4u ru, rv;
#pragma unroll
      for (int j = 0; j < 4; ++j) {
        float t = r.f[j] + bias[n + j];
        ru.f[j] = t + pbu[n + j];
        rv.f[j] = t + pbv[n + j];
      }
      int b = m >> 10, s = m & 1023, h = n >> 6, dk = n & 63;
      size_t idx = (size_t)(((b * 8 + h) << 10) + s) * 64 + dk;
      *(float4*)(out1 + idx) = ru.v;
      *(float4*)(out2 + idx) = rv.v;
    } else if constexpr (MODE == 2) {
      int h = n >> 6, dk = n & 63;
      *(float4*)(out1 + (size_t)(h * P_LEN + m) * 64 + dk) = r.v;
    } else {
#pragma unroll
      for (int j = 0; j < 4; ++j) r.f[j] += bias[n + j];
      *(float4*)(out1 + (size_t)m * 512 + n) = r.v;
    }
  }
}

// ---------------- fused rel-pos flash attention ---------------------------
// 1-D grid of 2048 blocks, XCD-aware decode: xcd = bid&7 (HW round-robin),
// XCD x sweeps batch b=x, heads sequential, 32 s-tiles per head.
// Concurrent window per XCD = 64 blocks = 2 bh -> K/V+pp hot set ~1.5MB < 4MB L2.
__global__ __launch_bounds__(256, 2) void attn_kernel(
    const float* __restrict__ qu, const float* __restrict__ qv,
    const float* __restrict__ kh, const float* __restrict__ vh,
    const float* __restrict__ pp, const int* __restrict__ mw,
    float* __restrict__ ctx)
{
  __shared__ float qu_s[QT * 64], qv_s[QT * 64];
  __shared__ float kh_s[KT * 64], vh_s[KT * 64];
  __shared__ float band_s[BAND_ROWS * 64];
  __shared__ float P_s[QT * 64];

  const int tid = threadIdx.x;
  const int ty = tid >> 4, tx = tid & 15;
  const int bid = blockIdx.x;
  const int xcd = bid & 7;
  const int i0 = bid >> 3;                 // [0,256)
  const int bh = (xcd << 3) + (i0 >> 5);   // b = xcd, h = i0>>5
  const int s0 = (i0 & 31) * QT;
  const int b = bh >> 3, h = bh & 7;

  const float* quB = qu + (size_t)bh * S_LEN * 64;
  const float* qvB = qv + (size_t)bh * S_LEN * 64;
  const float* khB = kh + (size_t)bh * S_LEN * 64;
  const float* vhB = vh + (size_t)bh * S_LEN * 64;
  const float* ppH = pp + (size_t)h * P_LEN * 64;

  // stage q tiles (swizzled)
#pragma unroll
  for (int it = 0; it < 2; ++it) {
    int idx = tid + it * 256;
    int r = idx >> 4, c = (idx & 15) << 2;
    *(float4*)&qu_s[SW(r, c)] = *(const float4*)(quB + (size_t)(s0 + r) * 64 + c);
    *(float4*)&qv_s[SW(r, c)] = *(const float4*)(qvB + (size_t)(s0 + r) * 64 + c);
  }
  __syncthreads();

  // rel_shift wrap element: z[0,S-1] = qv[1] . pp[0]  (only s0==0 blocks)
  float wrapW = 0.f;
  if (s0 == 0) {
    for (int d = 0; d < 64; ++d)
      wrapW = fmaf(qv_s[64 + d], ppH[d], wrapW);   // SW(1,d)=64+d
  }
  const bool wrapT = (s0 == 0) && (ty == 0) && (tx == 15);

  float m_run[2] = {-1e30f, -1e30f};
  float l_run[2] = {0.f, 0.f};
  float o[2][4] = {};
  const int ub = 4 * tx - 2 * ty + 31;   // band row for (i=0,j=0); offsets -1..+3

  for (int t0 = 0; t0 < S_LEN; t0 += KT) {
    // ---- stage K/V (64 rows) + band (95 rows), all swizzled
#pragma unroll
    for (int it = 0; it < 4; ++it) {
      int idx = tid + it * 256;
      int r = idx >> 4, c = (idx & 15) << 2;
      *(float4*)&kh_s[SW(r, c)] = *(const float4*)(khB + (size_t)(t0 + r) * 64 + c);
      *(float4*)&vh_s[SW(r, c)] = *(const float4*)(vhB + (size_t)(t0 + r) * 64 + c);
    }
    const int pmin = 993 + t0 - s0;   // band_s[u] = pp[pmin+u], u in [0,95)
#pragma unroll
    for (int it = 0; it < 6; ++it) {
      int idx = tid + it * 256;
      if (idx < BAND_ROWS * 16) {
        int r = idx >> 4, c = (idx & 15) << 2;
        int p = pmin + r;
        float4 bv = make_float4(0.f, 0.f, 0.f, 0.f);
        if (p < P_LEN) bv = *(const float4*)(ppH + (size_t)p * 64 + c);
        *(float4*)&band_s[SW(r, c)] = bv;
      }
    }
    __syncthreads();

    // ---- ac[i][j] = qu[2ty+i] . k[4tx+j]
    float ac[2][4] = {};
#pragma unroll
    for (int d = 0; d < 64; d += 4) {
      f4u qa0, qa1, kv0, kv1, kv2, kv3;
      qa0.v = *(float4*)&qu_s[SW(2 * ty + 0, d)];
      qa1.v = *(float4*)&qu_s[SW(2 * ty + 1, d)];
      kv0.v = *(float4*)&kh_s[SW(4 * tx + 0, d)];
      kv1.v = *(float4*)&kh_s[SW(4 * tx + 1, d)];
      kv2.v = *(float4*)&kh_s[SW(4 * tx + 2, d)];
      kv3.v = *(float4*)&kh_s[SW(4 * tx + 3, d)];
#pragma unroll
      for (int e = 0; e < 4; ++e) {
        ac[0][0] = fmaf(qa0.f[e], kv0.f[e], ac[0][0]);
        ac[0][1] = fmaf(qa0.f[e], kv1.f[e], ac[0][1]);
        ac[0][2] = fmaf(qa0.f[e], kv2.f[e], ac[0][2]);
        ac[0][3] = fmaf(qa0.f[e], kv3.f[e], ac[0][3]);
        ac[1][0] = fmaf(qa1.f[e], kv0.f[e], ac[1][0]);
        ac[1][1] = fmaf(qa1.f[e], kv1.f[e], ac[1][1]);
        ac[1][2] = fmaf(qa1.f[e], kv2.f[e], ac[1][2]);
        ac[1][3] = fmaf(qa1.f[e], kv3.f[e], ac[1][3]);
      }
    }

    // ---- bd[i][j] = qv[2ty+i] . band[ub + j - i]
    float bd[2][4] = {};
#pragma unroll
    for (int d = 0; d < 64; d += 4) {
      f4u qb0, qb1, b0, b1, b2, b3, b4;
      qb0.v = *(float4*)&qv_s[SW(2 * ty + 0, d)];
      qb1.v = *(float4*)&qv_s[SW(2 * ty + 1, d)];
      b0.v = *(float4*)&band_s[SW(ub - 1, d)];
      b1.v = *(float4*)&band_s[SW(ub + 0, d)];
      b2.v = *(float4*)&band_s[SW(ub + 1, d)];
      b3.v = *(float4*)&band_s[SW(ub + 2, d)];
      b4.v = *(float4*)&band_s[SW(ub + 3, d)];
#pragma unroll
      for (int e = 0; e < 4; ++e) {
        bd[0][0] = fmaf(qb0.f[e], b1.f[e], bd[0][0]);
        bd[0][1] = fmaf(qb0.f[e], b2.f[e], bd[0][1]);
        bd[0][2] = fmaf(qb0.f[e], b3.f[e], bd[0][2]);
        bd[0][3] = fmaf(qb0.f[e], b4.f[e], bd[0][3]);
        bd[1][0] = fmaf(qb1.f[e], b0.f[e], bd[1][0]);
        bd[1][1] = fmaf(qb1.f[e], b1.f[e], bd[1][1]);
        bd[1][2] = fmaf(qb1.f[e], b2.f[e], bd[1][2]);
        bd[1][3] = fmaf(qb1.f[e], b3.f[e], bd[1][3]);
      }
    }

    // ---- mask + online softmax (row r spans 16 lanes: shfl width 16)
    const int4 m4 = *(const int4*)(mw + (size_t)b * S_LEN + t0 + 4 * tx);
    const int mm[4] = {m4.x, m4.y, m4.z, m4.w};
#pragma unroll
    for (int i = 0; i < 2; ++i) {
      float sc[4];
#pragma unroll
      for (int j = 0; j < 4; ++j) {
        float bdv = bd[i][j];
        if (wrapT && i == 0 && j == 3 && t0 == S_LEN - KT) bdv = wrapW;
        float v = (ac[i][j] + bdv) * 0.125f;
        if (mm[j]) v = -10000.0f;
        sc[j] = v;
      }
      float tm = fmaxf(fmaxf(sc[0], sc[1]), fmaxf(sc[2], sc[3]));
#pragma unroll
      for (int off = 1; off < 16; off <<= 1) tm = fmaxf(tm, __shfl_xor(tm, off));
      float mn = fmaxf(m_run[i], tm);
      float corr = __expf(m_run[i] - mn);
      m_run[i] = mn;
      f4u pw;
      float ps = 0.f;
#pragma unroll
      for (int j = 0; j < 4; ++j) { pw.f[j] = __expf(sc[j] - mn); ps += pw.f[j]; }
#pragma unroll
      for (int off = 1; off < 16; off <<= 1) ps += __shfl_xor(ps, off);
      l_run[i] = l_run[i] * corr + ps;
#pragma unroll
      for (int j = 0; j < 4; ++j) o[i][j] *= corr;
      *(float4*)&P_s[SW(2 * ty + i, 4 * tx)] = pw.v;
    }
    // P_s exchange is within each 16-lane group -> no barrier needed

    // ---- PV: o[i][j] += sum_t P[2ty+i][t] * V[t][4tx+j]
#pragma unroll
    for (int t = 0; t < KT; t += 4) {
      f4u p0, p1, vv0, vv1, vv2, vv3;
      p0.v = *(float4*)&P_s[SW(2 * ty + 0, t)];
      p1.v = *(float4*)&P_s[SW(2 * ty + 1, t)];
      vv0.v = *(float4*)&vh_s[SW(t + 0, 4 * tx)];
      vv1.v = *(float4*)&vh_s[SW(t + 1, 4 * tx)];
      vv2.v = *(float4*)&vh_s[SW(t + 2, 4 * tx)];
      vv3.v = *(float4*)&vh_s[SW(t + 3, 4 * tx)];
#pragma unroll
      for (int j = 0; j < 4; ++j) {
        o[0][j] = fmaf(p0.f[0], vv0.f[j], o[0][j]);
        o[0][j] = fmaf(p0.f[1], vv1.f[j], o[0][j]);
        o[0][j] = fmaf(p0.f[2], vv2.f[j], o[0][j]);
        o[0][j] = fmaf(p0.f[3], vv3.f[j], o[0][j]);
        o[1][j] = fmaf(p1.f[0], vv0.f[j], o[1][j]);
        o[1][j] = fmaf(p1.f[1], vv1.f[j], o[1][j]);
        o[1][j] = fmaf(p1.f[2], vv2.f[j], o[1][j]);
        o[1][j] = fmaf(p1.f[3], vv3.f[j], o[1][j]);
      }
    }
    __syncthreads();   // protect kh/vh/band before next staging
  }

#pragma unroll
  for (int i = 0; i < 2; ++i) {
    int s = s0 + 2 * ty + i;
    float inv = 1.0f / l_run[i];
    f4u r;
#pragma unroll
    for (int j = 0; j < 4; ++j) r.f[j] = o[i][j] * inv;
    *(float4*)(ctx + ((size_t)b * S_LEN + s) * 512 + h * 64 + 4 * tx) = r.v;
  }
}

// --------------------------------------------------------------------------
extern "C" void kernel_launch(void* const* d_in, const int* in_sizes, int n_in,
                              void* d_out, int out_size, void* d_ws, size_t ws_size,
                              hipStream_t stream) {
  const float* q    = (const float*)d_in[0];
  const float* k    = (const float*)d_in[1];
  const float* v    = (const float*)d_in[2];
  const float* pos  = (const float*)d_in[3];
  const void*  mask = d_in[4];
  const float* Wq   = (const float*)d_in[5];
  const float* bq   = (const float*)d_in[6];
  const float* Wk   = (const float*)d_in[7];
  const float* bk   = (const float*)d_in[8];
  const float* Wv   = (const float*)d_in[9];
  const float* bv   = (const float*)d_in[10];
  const float* Wo   = (const float*)d_in[11];
  const float* bo   = (const float*)d_in[12];
  const float* Wpos = (const float*)d_in[13];
  const float* pbu  = (const float*)d_in[14];
  const float* pbv  = (const float*)d_in[15];
  float* out = (float*)d_out;

  float* ws = (float*)d_ws;
  const size_t SZ_BHSD = (size_t)B_SZ * N_HEAD * S_LEN * DKK;
  const size_t SZ_PP   = (size_t)N_HEAD * P_LEN * DKK;
  float* quW  = ws;
  float* qvW  = quW + SZ_BHSD;
  float* khW  = qvW + SZ_BHSD;
  float* vhW  = khW + SZ_BHSD;
  float* ppW  = vhW + SZ_BHSD;
  float* ctxW = ppW + SZ_PP;
  int*   mwW  = (int*)(ctxW + SZ_BHSD);

  mask_prep<<<dim3(B_SZ * S_LEN / 256), 256, 0, stream>>>(mask, mwW);

  gemm512<1><<<dim3(128, 8), 256, 0, stream>>>(q, Wq, bq, pbu, pbv, quW, qvW, 8192);
  gemm512<0><<<dim3(128, 8), 256, 0, stream>>>(k, Wk, bk, nullptr, nullptr, khW, nullptr, 8192);
  gemm512<0><<<dim3(128, 8), 256, 0, stream>>>(v, Wv, bv, nullptr, nullptr, vhW, nullptr, 8192);
  gemm512<2><<<dim3(32, 8), 256, 0, stream>>>(pos, Wpos, nullptr, nullptr, nullptr, ppW, nullptr, P_LEN);

  attn_kernel<<<dim3(2048), 256, 0, stream>>>(
      quW, qvW, khW, vhW, ppW, mwW, ctxW);

  gemm512<3><<<dim3(128, 8), 256, 0, stream>>>(ctxW, Wo, bo, nullptr, nullptr, out, nullptr, 8192);
}

// Round 7
// 876.867 us; speedup vs baseline: 2.4612x; 1.3268x over previous
//
#include <hip/hip_runtime.h>
#include <math.h>

#define S_LEN 1024
#define N_HEAD 8
#define P_LEN 2047
#define B_SZ 8
#define QT 32
#define KT 32

typedef __attribute__((ext_vector_type(8))) short bf16x8;
typedef __attribute__((ext_vector_type(4))) float f32x4;

union f4u { float4 v; float f[4]; };
union bfz { bf16x8 v; uint4 u; };

__device__ __forceinline__ unsigned short f2bf(float x) {
  unsigned b = __float_as_uint(x);
  b = b + 0x7FFF + ((b >> 16) & 1);
  return (unsigned short)(b >> 16);
}
__device__ __forceinline__ float bf2f(unsigned short h) {
  return __uint_as_float(((unsigned)h) << 16);
}

// ---------------- mask normalize ------------------------------------------
__global__ __launch_bounds__(256) void mask_prep(const void* __restrict__ mask,
                                                 int* __restrict__ mw) {
  const unsigned int* u = (const unsigned int*)mask;
  bool all01 = true, allf = true;
#pragma unroll
  for (int j = 0; j < 16; ++j) {
    unsigned int x = u[j];
    all01 &= (x <= 1u);
    allf &= (x == 0u || x == 0x3f800000u);
  }
  int i = blockIdx.x * 256 + threadIdx.x;
  int v;
  if (all01) v = (((const int*)mask)[i] != 0);
  else if (allf) v = (((const float*)mask)[i] != 0.0f);
  else v = (((const unsigned char*)mask)[i] != 0);
  mw[i] = v;
}

// ---------------- C = A(MxK) @ W(NxK)^T + bias, K=N=512 -------------------
// MODE 0: k/v proj -> bf16 hi/lo planes (B,H,S,64)
// MODE 1: q proj   -> qu=+bq+pbu, qv=+bq+pbv hi/lo planes
// MODE 2: pos proj -> hi/lo planes (H,P,64), M=2047
// MODE 3: out proj -> f32 (M,512)
template<int MODE>
__global__ __launch_bounds__(256) void gemm512(
    const float* __restrict__ A, const float* __restrict__ W,
    const float* __restrict__ bias, const float* __restrict__ pbu,
    const float* __restrict__ pbv, float* __restrict__ fo,
    unsigned short* __restrict__ o1h, unsigned short* __restrict__ o1l,
    unsigned short* __restrict__ o2h, unsigned short* __restrict__ o2l,
    int M)
{
  __shared__ float As[64][36];
  __shared__ float Wt[32][68];
  const int tid = threadIdx.x;
  const int ty = tid >> 4, tx = tid & 15;
  const int m0 = blockIdx.x * 64, n0 = blockIdx.y * 64;
  const int lr = tid >> 3;
  const int lc = (tid & 7) << 2;
  float acc[4][4] = {};

  for (int k0 = 0; k0 < 512; k0 += 32) {
#pragma unroll
    for (int hh = 0; hh < 2; ++hh) {
      int r = lr + hh * 32;
      int gm = m0 + r;
      float4 av = make_float4(0.f, 0.f, 0.f, 0.f);
      if (gm < M) av = *(const float4*)(A + (size_t)gm * 512 + k0 + lc);
      *(float4*)&As[r][lc] = av;
      float4 wv = *(const float4*)(W + (size_t)(n0 + r) * 512 + k0 + lc);
      Wt[lc + 0][r] = wv.x;
      Wt[lc + 1][r] = wv.y;
      Wt[lc + 2][r] = wv.z;
      Wt[lc + 3][r] = wv.w;
    }
    __syncthreads();
#pragma unroll
    for (int kk = 0; kk < 32; kk += 4) {
      f4u a[4], w[4];
#pragma unroll
      for (int i = 0; i < 4; ++i) a[i].v = *(float4*)&As[ty * 4 + i][kk];
#pragma unroll
      for (int q = 0; q < 4; ++q) w[q].v = *(float4*)&Wt[kk + q][tx * 4];
#pragma unroll
      for (int i = 0; i < 4; ++i)
#pragma unroll
        for (int q = 0; q < 4; ++q)
#pragma unroll
          for (int j = 0; j < 4; ++j)
            acc[i][j] = fmaf(a[i].f[q], w[q].f[j], acc[i][j]);
    }
    __syncthreads();
  }

#pragma unroll
  for (int i = 0; i < 4; ++i) {
    int m = m0 + ty * 4 + i;
    if (MODE == 2 && m >= M) continue;
    int n = n0 + tx * 4;
    if constexpr (MODE == 3) {
      f4u r;
#pragma unroll
      for (int j = 0; j < 4; ++j) r.f[j] = acc[i][j] + bias[n + j];
      *(float4*)(fo + (size_t)m * 512 + n) = r.v;
    } else if constexpr (MODE == 2) {
      int hI = n >> 6, dk = n & 63;
      size_t idx = ((size_t)(hI * P_LEN + m) << 6) + dk;
      ushort4 hv, lv;
      unsigned short h;
      h = f2bf(acc[i][0]); hv.x = h; lv.x = f2bf(acc[i][0] - bf2f(h));
      h = f2bf(acc[i][1]); hv.y = h; lv.y = f2bf(acc[i][1] - bf2f(h));
      h = f2bf(acc[i][2]); hv.z = h; lv.z = f2bf(acc[i][2] - bf2f(h));
      h = f2bf(acc[i][3]); hv.w = h; lv.w = f2bf(acc[i][3] - bf2f(h));
      *(ushort4*)(o1h + idx) = hv;
      *(ushort4*)(o1l + idx) = lv;
    } else {
      int bI = m >> 10, s = m & 1023, hI = n >> 6, dk = n & 63;
      size_t idx = ((size_t)(((bI * 8 + hI) << 10) + s) << 6) + dk;
      float vb[4];
#pragma unroll
      for (int j = 0; j < 4; ++j) vb[j] = acc[i][j] + bias[n + j];
      if constexpr (MODE == 0) {
        ushort4 hv, lv;
        unsigned short h;
        h = f2bf(vb[0]); hv.x = h; lv.x = f2bf(vb[0] - bf2f(h));
        h = f2bf(vb[1]); hv.y = h; lv.y = f2bf(vb[1] - bf2f(h));
        h = f2bf(vb[2]); hv.z = h; lv.z = f2bf(vb[2] - bf2f(h));
        h = f2bf(vb[3]); hv.w = h; lv.w = f2bf(vb[3] - bf2f(h));
        *(ushort4*)(o1h + idx) = hv;
        *(ushort4*)(o1l + idx) = lv;
      } else {  // MODE 1
        ushort4 hu, lu, hv2, lv2;
        unsigned short h;
        float t;
        t = vb[0] + pbu[n + 0]; h = f2bf(t); hu.x = h; lu.x = f2bf(t - bf2f(h));
        t = vb[1] + pbu[n + 1]; h = f2bf(t); hu.y = h; lu.y = f2bf(t - bf2f(h));
        t = vb[2] + pbu[n + 2]; h = f2bf(t); hu.z = h; lu.z = f2bf(t - bf2f(h));
        t = vb[3] + pbu[n + 3]; h = f2bf(t); hu.w = h; lu.w = f2bf(t - bf2f(h));
        t = vb[0] + pbv[n + 0]; h = f2bf(t); hv2.x = h; lv2.x = f2bf(t - bf2f(h));
        t = vb[1] + pbv[n + 1]; h = f2bf(t); hv2.y = h; lv2.y = f2bf(t - bf2f(h));
        t = vb[2] + pbv[n + 2]; h = f2bf(t); hv2.z = h; lv2.z = f2bf(t - bf2f(h));
        t = vb[3] + pbv[n + 3]; h = f2bf(t); hv2.w = h; lv2.w = f2bf(t - bf2f(h));
        *(ushort4*)(o1h + idx) = hu;  *(ushort4*)(o1l + idx) = lu;
        *(ushort4*)(o2h + idx) = hv2; *(ushort4*)(o2l + idx) = lv2;
      }
    }
  }
}

// ---------------- V transpose: (BH,S,64) -> (BH,64,S), both planes --------
__global__ __launch_bounds__(256) void vtrans(
    const unsigned short* __restrict__ src_h, const unsigned short* __restrict__ src_l,
    unsigned short* __restrict__ dst_h, unsigned short* __restrict__ dst_l)
{
  __shared__ unsigned short tile[64 * 72];
  const int tid = threadIdx.x;
  const int bh = blockIdx.x >> 4, st = blockIdx.x & 15;
  const int s0 = st << 6;
  const int r = tid >> 2;
  const int c0 = (tid & 3) << 4;
  const size_t ibase = (((size_t)(bh << 10) + s0 + r) << 6) + c0;
  const size_t obase = ((size_t)(bh << 6)) << 10;
#pragma unroll
  for (int pl = 0; pl < 2; ++pl) {
    const unsigned short* src = pl ? src_l : src_h;
    unsigned short* dst = pl ? dst_l : dst_h;
    *(uint4*)&tile[r * 72 + c0] = *(const uint4*)(src + ibase);
    *(uint4*)&tile[r * 72 + c0 + 8] = *(const uint4*)(src + ibase + 8);
    __syncthreads();
    unsigned short buf[16] __attribute__((aligned(16)));
#pragma unroll
    for (int i = 0; i < 16; ++i) buf[i] = tile[(c0 + i) * 72 + r];
    *(uint4*)(dst + obase + ((size_t)r << 10) + s0 + c0) = *(uint4*)&buf[0];
    *(uint4*)(dst + obase + ((size_t)r << 10) + s0 + c0 + 8) = *(uint4*)&buf[8];
    __syncthreads();
  }
}

// ---------------- fused rel-pos flash attention (bf16-split MFMA) ---------
// 2048 blocks (XCD decode), 256 thr = 4 waves. QT=32 rows, KT=32 keys.
// wave wid: rt=wid>>1 (row-tile), ct=wid&1 (col/dk-half).
// mfma_f32_16x16x32_bf16 layouts: A row=l&15,k=8*(l>>4)+i; B col=l&15,same k;
// D row=4*(l>>4)+reg, col=l&15. 3-term split: ah*bh + ah*bl + al*bh.
__global__ __launch_bounds__(256, 3) void attn_kernel(
    const unsigned short* __restrict__ quh, const unsigned short* __restrict__ qul,
    const unsigned short* __restrict__ qvh, const unsigned short* __restrict__ qvl,
    const unsigned short* __restrict__ khh, const unsigned short* __restrict__ khl,
    const unsigned short* __restrict__ vth, const unsigned short* __restrict__ vtl,
    const unsigned short* __restrict__ pph, const unsigned short* __restrict__ ppl,
    const int* __restrict__ mw, float* __restrict__ ctx)
{
  __shared__ float zs[32 * 68];                 // rel-pos Z tile (rows x u)
  __shared__ unsigned short ph_s[32 * 40], pl_s[32 * 40];
  __shared__ float red[2][32][2];               // [ct][row][{max,sumexp}]

  const int tid = threadIdx.x;
  const int wid = tid >> 6, lane = tid & 63;
  const int g = lane >> 4, ln = lane & 15;
  const int rt = wid >> 1, ct = wid & 1;
  const int R0 = rt << 4, T0 = ct << 4;

  const int bid = blockIdx.x;
  const int xcd = bid & 7;
  const int i0 = bid >> 3;
  const int bh = (xcd << 3) + (i0 >> 5);
  const int s0 = (i0 & 31) * QT;
  const int b = bh >> 3, h = bh & 7;

  const size_t qbase = ((size_t)((bh << 10) + s0)) << 6;
  const size_t kbase = ((size_t)(bh << 10)) << 6;
  const size_t vtb = ((size_t)(bh << 6)) << 10;
  const size_t ppb = ((size_t)(h * P_LEN)) << 6;

  // ---- preload Q fragments (block-resident, reused every K-tile)
  bf16x8 qa_h[2], qa_l[2], qb_h[2], qb_l[2];
  {
    const size_t qo = qbase + (((size_t)(R0 + ln)) << 6) + (g << 3);
#pragma unroll
    for (int dblk = 0; dblk < 2; ++dblk) {
      qa_h[dblk] = *(const bf16x8*)(quh + qo + dblk * 32);
      qa_l[dblk] = *(const bf16x8*)(qul + qo + dblk * 32);
      qb_h[dblk] = *(const bf16x8*)(qvh + qo + dblk * 32);
      qb_l[dblk] = *(const bf16x8*)(qvl + qo + dblk * 32);
    }
  }

  // ---- rel_shift wrap element z[0,1023] = qv[1] . pp[0]
  float wrapW = 0.f;
  if (s0 == 0) {
    const unsigned short* q1h = qvh + ((((size_t)(bh << 10)) + 1) << 6);
    const unsigned short* q1l = qvl + ((((size_t)(bh << 10)) + 1) << 6);
    for (int d = 0; d < 64; ++d)
      wrapW += (bf2f(q1h[d]) + bf2f(q1l[d])) * (bf2f(pph[ppb + d]) + bf2f(ppl[ppb + d]));
  }
  const bool wrapT = (s0 == 0) && (wid == 1) && (lane == 15);

  f32x4 oA[2] = {{0.f, 0.f, 0.f, 0.f}, {0.f, 0.f, 0.f, 0.f}};
  float m_run[4], l_run[4];
#pragma unroll
  for (int r = 0; r < 4; ++r) { m_run[r] = -1e30f; l_run[r] = 0.f; }

  for (int t0 = 0; t0 < S_LEN; t0 += KT) {
    // ---- ac = (q+u) . K^T  (16x16 tile per wave)
    f32x4 ac = {0.f, 0.f, 0.f, 0.f};
    {
      const size_t ko = kbase + (((size_t)(t0 + T0 + ln)) << 6) + (g << 3);
#pragma unroll
      for (int dblk = 0; dblk < 2; ++dblk) {
        bf16x8 kh_ = *(const bf16x8*)(khh + ko + dblk * 32);
        bf16x8 kl_ = *(const bf16x8*)(khl + ko + dblk * 32);
        ac = __builtin_amdgcn_mfma_f32_16x16x32_bf16(qa_l[dblk], kh_, ac, 0, 0, 0);
        ac = __builtin_amdgcn_mfma_f32_16x16x32_bf16(qa_h[dblk], kl_, ac, 0, 0, 0);
        ac = __builtin_amdgcn_mfma_f32_16x16x32_bf16(qa_h[dblk], kh_, ac, 0, 0, 0);
      }
    }
    // ---- Z = (q+v) . band^T  (banded rel-pos scores, 2 u-tiles per wave)
    const int pmin = 993 + t0 - s0;
#pragma unroll
    for (int ut = 0; ut < 2; ++ut) {
      const int U0 = (ct << 5) + (ut << 4);
      const int p = pmin + U0 + ln;
      f32x4 z = {0.f, 0.f, 0.f, 0.f};
      bfz bh_[2], bl_[2];
      if (p < P_LEN) {
        const size_t po = ppb + (((size_t)p) << 6) + (g << 3);
        bh_[0].v = *(const bf16x8*)(pph + po);
        bh_[1].v = *(const bf16x8*)(pph + po + 32);
        bl_[0].v = *(const bf16x8*)(ppl + po);
        bl_[1].v = *(const bf16x8*)(ppl + po + 32);
      } else {
        bh_[0].u = bh_[1].u = bl_[0].u = bl_[1].u = make_uint4(0, 0, 0, 0);
      }
#pragma unroll
      for (int dblk = 0; dblk < 2; ++dblk) {
        z = __builtin_amdgcn_mfma_f32_16x16x32_bf16(qb_l[dblk], bh_[dblk].v, z, 0, 0, 0);
        z = __builtin_amdgcn_mfma_f32_16x16x32_bf16(qb_h[dblk], bl_[dblk].v, z, 0, 0, 0);
        z = __builtin_amdgcn_mfma_f32_16x16x32_bf16(qb_h[dblk], bh_[dblk].v, z, 0, 0, 0);
      }
#pragma unroll
      for (int r = 0; r < 4; ++r)
        zs[(R0 + (g << 2) + r) * 68 + U0 + ln] = z[r];
    }
    __syncthreads();   // zs ready

    // ---- scores + in-wave softmax partials
    const int t = T0 + ln;
    const int mval = mw[(b << 10) + t0 + t];
    float sc[4], ml[4], sl[4];
#pragma unroll
    for (int r = 0; r < 4; ++r) {
      const int row = R0 + (g << 2) + r;
      float bdv = zs[row * 68 + (t - row + 31)];
      if (wrapT && r == 0 && t0 == S_LEN - KT) bdv = wrapW;
      float v = (ac[r] + bdv) * 0.125f;
      sc[r] = mval ? -10000.f : v;
    }
#pragma unroll
    for (int r = 0; r < 4; ++r) {
      float mx = sc[r];
#pragma unroll
      for (int off = 1; off < 16; off <<= 1) mx = fmaxf(mx, __shfl_xor(mx, off));
      ml[r] = mx;
      float e = __expf(sc[r] - mx);
      float s = e;
#pragma unroll
      for (int off = 1; off < 16; off <<= 1) s += __shfl_xor(s, off);
      sl[r] = s;
      sc[r] = e;   // stash exp(sc - ml)
    }
    if (ln == 0) {
#pragma unroll
      for (int r = 0; r < 4; ++r) {
        red[ct][R0 + (g << 2) + r][0] = ml[r];
        red[ct][R0 + (g << 2) + r][1] = sl[r];
      }
    }
    __syncthreads();   // partials published

    // ---- combine halves, rescale, emit P (bf16 hi/lo)
#pragma unroll
    for (int r = 0; r < 4; ++r) {
      const int row = R0 + (g << 2) + r;
      const float mo = red[ct ^ 1][row][0];
      const float so = red[ct ^ 1][row][1];
      const float mn = fmaxf(m_run[r], fmaxf(ml[r], mo));
      const float corr = __expf(m_run[r] - mn);
      l_run[r] = l_run[r] * corr + sl[r] * __expf(ml[r] - mn) + so * __expf(mo - mn);
      m_run[r] = mn;
      oA[0][r] *= corr;
      oA[1][r] *= corr;
      const float p = sc[r] * __expf(ml[r] - mn);
      const unsigned short hp = f2bf(p);
      ph_s[row * 40 + t] = hp;
      pl_s[row * 40 + t] = f2bf(p - bf2f(hp));
    }
    __syncthreads();   // P ready

    // ---- PV: O += P . V  (V pre-transposed (BH,64,S))
    bf16x8 pa_h = *(const bf16x8*)&ph_s[(R0 + ln) * 40 + (g << 3)];
    bf16x8 pa_l = *(const bf16x8*)&pl_s[(R0 + ln) * 40 + (g << 3)];
#pragma unroll
    for (int dkt = 0; dkt < 2; ++dkt) {
      const int dk = (ct << 5) + (dkt << 4) + ln;
      const size_t vo = vtb + (((size_t)dk) << 10) + t0 + (g << 3);
      bf16x8 vh_ = *(const bf16x8*)(vth + vo);
      bf16x8 vl_ = *(const bf16x8*)(vtl + vo);
      oA[dkt] = __builtin_amdgcn_mfma_f32_16x16x32_bf16(pa_l, vh_, oA[dkt], 0, 0, 0);
      oA[dkt] = __builtin_amdgcn_mfma_f32_16x16x32_bf16(pa_h, vl_, oA[dkt], 0, 0, 0);
      oA[dkt] = __builtin_amdgcn_mfma_f32_16x16x32_bf16(pa_h, vh_, oA[dkt], 0, 0, 0);
    }
    // no barrier needed here: next iter's zs writes are fenced by barrier A,
    // and P/red rewrites are fenced by barriers A+B.
  }

  // ---- epilogue
#pragma unroll
  for (int r = 0; r < 4; ++r) {
    const float inv = 1.0f / l_run[r];
    const int s = s0 + R0 + (g << 2) + r;
    float* cp = ctx + (((size_t)((b << 10) + s)) << 9) + (h << 6);
    cp[(ct << 5) + ln] = oA[0][r] * inv;
    cp[(ct << 5) + 16 + ln] = oA[1][r] * inv;
  }
}

// --------------------------------------------------------------------------
extern "C" void kernel_launch(void* const* d_in, const int* in_sizes, int n_in,
                              void* d_out, int out_size, void* d_ws, size_t ws_size,
                              hipStream_t stream) {
  const float* q    = (const float*)d_in[0];
  const float* k    = (const float*)d_in[1];
  const float* v    = (const float*)d_in[2];
  const float* pos  = (const float*)d_in[3];
  const void*  mask = d_in[4];
  const float* Wq   = (const float*)d_in[5];
  const float* bq   = (const float*)d_in[6];
  const float* Wk   = (const float*)d_in[7];
  const float* bk   = (const float*)d_in[8];
  const float* Wv   = (const float*)d_in[9];
  const float* bv   = (const float*)d_in[10];
  const float* Wo   = (const float*)d_in[11];
  const float* bo   = (const float*)d_in[12];
  const float* Wpos = (const float*)d_in[13];
  const float* pbu  = (const float*)d_in[14];
  const float* pbv  = (const float*)d_in[15];
  float* out = (float*)d_out;

  unsigned short* us = (unsigned short*)d_ws;
  const size_t SZ  = (size_t)B_SZ * N_HEAD * S_LEN * 64;   // 4,194,304
  const size_t SZP = (size_t)N_HEAD * P_LEN * 64;          // 1,048,064
  unsigned short* quh = us;
  unsigned short* qul = quh + SZ;
  unsigned short* qvh = qul + SZ;
  unsigned short* qvl = qvh + SZ;
  unsigned short* khh = qvl + SZ;
  unsigned short* khl = khh + SZ;
  unsigned short* vth = khl + SZ;
  unsigned short* vtl = vth + SZ;
  unsigned short* pph = vtl + SZ;
  unsigned short* ppl = pph + SZP;
  float* ctxW = (float*)(ppl + SZP);
  // vh row-major planes overlay ctx (consumed by vtrans before attn writes ctx)
  unsigned short* vhh = (unsigned short*)ctxW;
  unsigned short* vhl = vhh + SZ;
  int* mwW = (int*)(ctxW + SZ);

  mask_prep<<<dim3(B_SZ * S_LEN / 256), 256, 0, stream>>>(mask, mwW);

  gemm512<1><<<dim3(128, 8), 256, 0, stream>>>(q, Wq, bq, pbu, pbv, nullptr,
                                               quh, qul, qvh, qvl, 8192);
  gemm512<0><<<dim3(128, 8), 256, 0, stream>>>(k, Wk, bk, nullptr, nullptr, nullptr,
                                               khh, khl, nullptr, nullptr, 8192);
  gemm512<0><<<dim3(128, 8), 256, 0, stream>>>(v, Wv, bv, nullptr, nullptr, nullptr,
                                               vhh, vhl, nullptr, nullptr, 8192);
  gemm512<2><<<dim3(32, 8), 256, 0, stream>>>(pos, Wpos, nullptr, nullptr, nullptr, nullptr,
                                              pph, ppl, nullptr, nullptr, P_LEN);

  vtrans<<<dim3(64 * 16), 256, 0, stream>>>(vhh, vhl, vth, vtl);

  attn_kernel<<<dim3(2048), 256, 0, stream>>>(quh, qul, qvh, qvl, khh, khl,
                                              vth, vtl, pph, ppl, mwW, ctxW);

  gemm512<3><<<dim3(128, 8), 256, 0, stream>>>(ctxW, Wo, bo, nullptr, nullptr, out,
                                               nullptr, nullptr, nullptr, nullptr, 8192);
}